// Round 1
// baseline (443.064 us; speedup 1.0000x reference)
//
#include <hip/hip_runtime.h>
#include <hip/hip_bf16.h>

typedef __attribute__((ext_vector_type(8))) short short8;
typedef __attribute__((ext_vector_type(4))) float f32x4;

// fp32 -> bf16 bits, round-to-nearest-even (self-contained)
static __device__ inline short f2bf(float f) {
    unsigned u = __float_as_uint(f);
    unsigned r = (u + 0x7fffu + ((u >> 16) & 1u)) >> 16;
    return (short)r;
}

__global__ void k_zero(float* p, int n) {
    for (int i = blockIdx.x * blockDim.x + threadIdx.x; i < n; i += gridDim.x * blockDim.x)
        p[i] = 0.f;
}

// Normalize each row of vectors -> V
__global__ __launch_bounds__(256) void k_normalize(const float* __restrict__ vec,
                                                   float* __restrict__ V, int dim) {
    int row = blockIdx.x;
    const float4* src = (const float4*)(vec + (size_t)row * dim);
    float4* dst = (float4*)(V + (size_t)row * dim);
    int nv4 = dim >> 2;
    float ss = 0.f;
    for (int i = threadIdx.x; i < nv4; i += blockDim.x) {
        float4 v = src[i];
        ss += v.x * v.x + v.y * v.y + v.z * v.z + v.w * v.w;
    }
    for (int off = 32; off; off >>= 1) ss += __shfl_down(ss, off, 64);
    __shared__ float ws_[4];
    int lane = threadIdx.x & 63, w = threadIdx.x >> 6;
    if (lane == 0) ws_[w] = ss;
    __syncthreads();
    float inv = 1.0f / sqrtf(ws_[0] + ws_[1] + ws_[2] + ws_[3]);
    for (int i = threadIdx.x; i < nv4; i += blockDim.x) {
        float4 v = src[i];
        v.x *= inv; v.y *= inv; v.z *= inv; v.w *= inv;
        dst[i] = v;
    }
}

__device__ inline void st8(float* p, float4 a, float4 b) {
    p[0] = a.x; p[1] = a.y; p[2] = a.z; p[3] = a.w;
    p[4] = b.x; p[5] = b.y; p[6] = b.z; p[7] = b.w;
}

// G = V * V^T   (G[j][k] = dot(row j, row k)), fp32
__global__ __launch_bounds__(256) void k_gram(const float* __restrict__ V,
                                              float* __restrict__ G, int m, int dim) {
    __shared__ float As[64 * 33];
    __shared__ float Bs[64 * 33];
    int j0 = blockIdx.y * 64, k0 = blockIdx.x * 64;
    int t = threadIdx.x, tx = t & 15, ty = t >> 4;
    float acc[4][4] = {};
    for (int d0 = 0; d0 < dim; d0 += 32) {
        __syncthreads();
        int r = t >> 2, c = (t & 3) * 8;
        const float4* pa = (const float4*)(V + (size_t)(j0 + r) * dim + d0 + c);
        const float4* pb = (const float4*)(V + (size_t)(k0 + r) * dim + d0 + c);
        float4 a0 = pa[0], a1 = pa[1];
        float4 b0 = pb[0], b1 = pb[1];
        st8(&As[r * 33 + c], a0, a1);
        st8(&Bs[r * 33 + c], b0, b1);
        __syncthreads();
#pragma unroll
        for (int dd = 0; dd < 32; ++dd) {
            float av[4], bv[4];
#pragma unroll
            for (int i = 0; i < 4; ++i) av[i] = As[(ty * 4 + i) * 33 + dd];
#pragma unroll
            for (int j = 0; j < 4; ++j) bv[j] = Bs[(tx * 4 + j) * 33 + dd];
#pragma unroll
            for (int i = 0; i < 4; ++i)
#pragma unroll
                for (int j = 0; j < 4; ++j) acc[i][j] += av[i] * bv[j];
        }
    }
#pragma unroll
    for (int i = 0; i < 4; ++i)
#pragma unroll
        for (int j = 0; j < 4; ++j)
            G[(size_t)(j0 + ty * 4 + i) * m + k0 + tx * 4 + j] = acc[i][j];
}

// Invert 64x64 diagonal blocks of R = 0.5 I + striu(G) -> T (per-column back-substitution)
__global__ __launch_bounds__(64) void k_baseinv(const float* __restrict__ G,
                                                float* __restrict__ T, int m) {
    __shared__ float R[64 * 65];
    __shared__ float X[64 * 65];
    int b0 = blockIdx.x * 64;
    int c = threadIdx.x;  // 0..63, one column per thread
    for (int r = 0; r < 64; ++r) {
        R[r * 65 + c] = (r < c) ? G[(size_t)(b0 + r) * m + b0 + c] : (r == c ? 0.5f : 0.f);
        X[r * 65 + c] = (r == c) ? 2.f : 0.f;
    }
    __syncthreads();
    // column c is private to thread c: no barriers needed
    for (int r = 62; r >= 0; --r) {
        float s = 0.f;
        for (int i = r + 1; i < 64; ++i) s += R[r * 65 + i] * X[i * 65 + c];
        if (r < c) X[r * 65 + c] = -2.f * s;
    }
    __syncthreads();
    for (int r = 0; r < 64; ++r)
        T[(size_t)(b0 + r) * m + b0 + c] = X[r * 65 + c];
}

// tree level: tmp_p = G_B * Cinv     (pair p at blockIdx.z, block size s)
__global__ __launch_bounds__(256) void k_tree_a(const float* __restrict__ G,
                                                const float* __restrict__ T,
                                                float* __restrict__ tmp, int m, int s) {
    int p = blockIdx.z;
    int a0 = 2 * p * s, c0 = a0 + s;
    int r0t = blockIdx.y * 64, c0t = blockIdx.x * 64;
    __shared__ float As[64 * 33];  // G rows  [64 r][32 k]
    __shared__ float Bs[32 * 65];  // T rows  [32 k][64 c]
    int t = threadIdx.x, tx = t & 15, ty = t >> 4;
    float acc[4][4] = {};
    for (int k0 = 0; k0 < s; k0 += 32) {
        __syncthreads();
        {
            int r = t >> 2, cc = (t & 3) * 8;
            const float4* pa = (const float4*)(G + (size_t)(a0 + r0t + r) * m + c0 + k0 + cc);
            st8(&As[r * 33 + cc], pa[0], pa[1]);
        }
        {
            int r = t >> 3, cc = (t & 7) * 8;
            const float4* pb = (const float4*)(T + (size_t)(c0 + k0 + r) * m + c0 + c0t + cc);
            st8(&Bs[r * 65 + cc], pb[0], pb[1]);
        }
        __syncthreads();
#pragma unroll
        for (int kk = 0; kk < 32; ++kk) {
            float av[4], bv[4];
#pragma unroll
            for (int i = 0; i < 4; ++i) av[i] = As[(ty * 4 + i) * 33 + kk];
#pragma unroll
            for (int j = 0; j < 4; ++j) bv[j] = Bs[kk * 65 + tx * 4 + j];
#pragma unroll
            for (int i = 0; i < 4; ++i)
#pragma unroll
                for (int j = 0; j < 4; ++j) acc[i][j] += av[i] * bv[j];
        }
    }
#pragma unroll
    for (int i = 0; i < 4; ++i)
#pragma unroll
        for (int j = 0; j < 4; ++j)
            tmp[(size_t)p * s * s + (size_t)(r0t + ty * 4 + i) * s + c0t + tx * 4 + j] = acc[i][j];
}

// tree level: T[a0.., c0..] = -Ainv * tmp_p
__global__ __launch_bounds__(256) void k_tree_b(float* __restrict__ T,
                                                const float* __restrict__ tmp, int m, int s) {
    int p = blockIdx.z;
    int a0 = 2 * p * s, c0 = a0 + s;
    int r0t = blockIdx.y * 64, c0t = blockIdx.x * 64;
    __shared__ float As[64 * 33];  // T diag block rows [64 r][32 k]
    __shared__ float Bs[32 * 65];  // tmp rows [32 k][64 c]
    int t = threadIdx.x, tx = t & 15, ty = t >> 4;
    float acc[4][4] = {};
    for (int k0 = 0; k0 < s; k0 += 32) {
        __syncthreads();
        {
            int r = t >> 2, cc = (t & 3) * 8;
            const float4* pa = (const float4*)(T + (size_t)(a0 + r0t + r) * m + a0 + k0 + cc);
            st8(&As[r * 33 + cc], pa[0], pa[1]);
        }
        {
            int r = t >> 3, cc = (t & 7) * 8;
            const float4* pb = (const float4*)(tmp + (size_t)p * s * s + (size_t)(k0 + r) * s + c0t + cc);
            st8(&Bs[r * 65 + cc], pb[0], pb[1]);
        }
        __syncthreads();
#pragma unroll
        for (int kk = 0; kk < 32; ++kk) {
            float av[4], bv[4];
#pragma unroll
            for (int i = 0; i < 4; ++i) av[i] = As[(ty * 4 + i) * 33 + kk];
#pragma unroll
            for (int j = 0; j < 4; ++j) bv[j] = Bs[kk * 65 + tx * 4 + j];
#pragma unroll
            for (int i = 0; i < 4; ++i)
#pragma unroll
                for (int j = 0; j < 4; ++j) acc[i][j] += av[i] * bv[j];
        }
    }
#pragma unroll
    for (int i = 0; i < 4; ++i)
#pragma unroll
        for (int j = 0; j < 4; ++j)
            T[(size_t)(a0 + r0t + ty * 4 + i) * m + c0 + c0t + tx * 4 + j] = -acc[i][j];
}

// W[d][k] = sum_j V[j][d] * T[j][k]
__global__ __launch_bounds__(256) void k_w(const float* __restrict__ V,
                                           const float* __restrict__ T,
                                           float* __restrict__ W, int m, int dim) {
    int d0 = blockIdx.y * 64, k0 = blockIdx.x * 64;
    __shared__ float Vs[32 * 65];  // [32 j][64 d]
    __shared__ float Ts[32 * 65];  // [32 j][64 k]
    int t = threadIdx.x, tx = t & 15, ty = t >> 4;
    float acc[4][4] = {};
    for (int j0 = 0; j0 < m; j0 += 32) {
        __syncthreads();
        int r = t >> 3, cc = (t & 7) * 8;
        const float4* pa = (const float4*)(V + (size_t)(j0 + r) * dim + d0 + cc);
        st8(&Vs[r * 65 + cc], pa[0], pa[1]);
        const float4* pb = (const float4*)(T + (size_t)(j0 + r) * m + k0 + cc);
        st8(&Ts[r * 65 + cc], pb[0], pb[1]);
        __syncthreads();
#pragma unroll
        for (int jj = 0; jj < 32; ++jj) {
            float av[4], bv[4];
#pragma unroll
            for (int i = 0; i < 4; ++i) av[i] = Vs[jj * 65 + ty * 4 + i];
#pragma unroll
            for (int j = 0; j < 4; ++j) bv[j] = Ts[jj * 65 + tx * 4 + j];
#pragma unroll
            for (int i = 0; i < 4; ++i)
#pragma unroll
                for (int j = 0; j < 4; ++j) acc[i][j] += av[i] * bv[j];
        }
    }
#pragma unroll
    for (int i = 0; i < 4; ++i)
#pragma unroll
        for (int j = 0; j < 4; ++j)
            W[(size_t)(d0 + ty * 4 + i) * m + k0 + tx * 4 + j] = acc[i][j];
}

// Qt[e][d] (bf16) = delta(e,d) - sum_k W[d][k] * V[k][e]
__global__ __launch_bounds__(256) void k_q(const float* __restrict__ W,
                                           const float* __restrict__ V,
                                           short* __restrict__ Qt, int m, int dim) {
    int e0 = blockIdx.y * 64, d0 = blockIdx.x * 64;
    __shared__ float Ws[64 * 33];  // [64 d][32 k]
    __shared__ float Vs[32 * 65];  // [32 k][64 e]
    int t = threadIdx.x, tx = t & 15, ty = t >> 4;
    float acc[4][4] = {};
    for (int k0 = 0; k0 < m; k0 += 32) {
        __syncthreads();
        {
            int r = t >> 2, cc = (t & 3) * 8;
            const float4* pa = (const float4*)(W + (size_t)(d0 + r) * m + k0 + cc);
            st8(&Ws[r * 33 + cc], pa[0], pa[1]);
        }
        {
            int r = t >> 3, cc = (t & 7) * 8;
            const float4* pb = (const float4*)(V + (size_t)(k0 + r) * dim + e0 + cc);
            st8(&Vs[r * 65 + cc], pb[0], pb[1]);
        }
        __syncthreads();
#pragma unroll
        for (int kk = 0; kk < 32; ++kk) {
            float ae[4], bd[4];
#pragma unroll
            for (int i = 0; i < 4; ++i) ae[i] = Vs[kk * 65 + ty * 4 + i];
#pragma unroll
            for (int j = 0; j < 4; ++j) bd[j] = Ws[(tx * 4 + j) * 33 + kk];
#pragma unroll
            for (int i = 0; i < 4; ++i)
#pragma unroll
                for (int j = 0; j < 4; ++j) acc[i][j] += ae[i] * bd[j];
        }
    }
#pragma unroll
    for (int i = 0; i < 4; ++i)
#pragma unroll
        for (int j = 0; j < 4; ++j) {
            int e = e0 + ty * 4 + i, d = d0 + tx * 4 + j;
            Qt[(size_t)e * dim + d] = f2bf(((e == d) ? 1.f : 0.f) - acc[i][j]);
        }
}

// out = x * Q + bias     (A = x cast to bf16 on the fly; B from Qt; MFMA 16x16x32)
__global__ __launch_bounds__(256) void k_apply(const float* __restrict__ x,
                                               const short* __restrict__ Qt,
                                               const float* __restrict__ bias,
                                               float* __restrict__ out, int n, int dim) {
    __shared__ short As[128 * 32];
    __shared__ short Bs[128 * 32];
    int m0 = blockIdx.y * 128, n0 = blockIdx.x * 128;
    int t = threadIdx.x;
    int lane = t & 63, wave = t >> 6;
    int wr = wave >> 1, wc = wave & 1;
    int srow = t >> 1, shalf = t & 1;
    f32x4 acc[4][4] = {};
    for (int k0 = 0; k0 < dim; k0 += 32) {
        __syncthreads();
        {   // stage A: 16 floats -> 16 bf16
            const float4* px = (const float4*)(x + (size_t)(m0 + srow) * dim + k0 + shalf * 16);
            float4 v0 = px[0], v1 = px[1], v2 = px[2], v3 = px[3];
            float fv[16];
            *(float4*)&fv[0] = v0; *(float4*)&fv[4] = v1;
            *(float4*)&fv[8] = v2; *(float4*)&fv[12] = v3;
            short sv[16];
#pragma unroll
            for (int q = 0; q < 16; ++q) sv[q] = f2bf(fv[q]);
            *(short8*)&As[srow * 32 + shalf * 16] = *(short8*)&sv[0];
            *(short8*)&As[srow * 32 + shalf * 16 + 8] = *(short8*)&sv[8];
        }
        {   // stage B from Qt (already bf16)
            const short8* pq = (const short8*)(Qt + (size_t)(n0 + srow) * dim + k0 + shalf * 16);
            short8 q0 = pq[0], q1 = pq[1];
            *(short8*)&Bs[srow * 32 + shalf * 16] = q0;
            *(short8*)&Bs[srow * 32 + shalf * 16 + 8] = q1;
        }
        __syncthreads();
        short8 af[4], bf_[4];
#pragma unroll
        for (int i = 0; i < 4; ++i)
            af[i] = *(const short8*)&As[(wr * 64 + i * 16 + (lane & 15)) * 32 + (lane >> 4) * 8];
#pragma unroll
        for (int j = 0; j < 4; ++j)
            bf_[j] = *(const short8*)&Bs[(wc * 64 + j * 16 + (lane & 15)) * 32 + (lane >> 4) * 8];
#pragma unroll
        for (int i = 0; i < 4; ++i)
#pragma unroll
            for (int j = 0; j < 4; ++j)
                acc[i][j] = __builtin_amdgcn_mfma_f32_16x16x32_bf16(af[i], bf_[j], acc[i][j], 0, 0, 0);
    }
#pragma unroll
    for (int i = 0; i < 4; ++i)
#pragma unroll
        for (int j = 0; j < 4; ++j) {
            int row = m0 + wr * 64 + i * 16 + (lane >> 4) * 4;
            int col = n0 + wc * 64 + j * 16 + (lane & 15);
            float b = bias[col];
#pragma unroll
            for (int r = 0; r < 4; ++r)
                out[(size_t)(row + r) * dim + col] = acc[i][j][r] + b;
        }
}

extern "C" void kernel_launch(void* const* d_in, const int* in_sizes, int n_in,
                              void* d_out, int out_size, void* d_ws, size_t ws_size,
                              hipStream_t stream) {
    const float* x = (const float*)d_in[0];
    const float* vec = (const float*)d_in[1];
    const float* bias = (const float*)d_in[2];
    float* out = (float*)d_out;

    int dim = in_sizes[2];
    int m = in_sizes[1] / dim;
    int n = in_sizes[0] / dim;

    float* V = (float*)d_ws;
    float* G = V + (size_t)m * dim;
    float* T = G + (size_t)m * m;
    float* W = T + (size_t)m * m;
    float* tmp = W + (size_t)dim * m;
    short* Qt = (short*)(tmp + (size_t)m * m / 4);

    k_zero<<<256, 256, 0, stream>>>(T, m * m);
    k_normalize<<<m, 256, 0, stream>>>(vec, V, dim);
    k_gram<<<dim3(m / 64, m / 64), 256, 0, stream>>>(V, G, m, dim);
    k_baseinv<<<m / 64, 64, 0, stream>>>(G, T, m);
    for (int s = 64; s < m; s <<= 1) {
        dim3 g(s / 64, s / 64, m / (2 * s));
        k_tree_a<<<g, 256, 0, stream>>>(G, T, tmp, m, s);
        k_tree_b<<<g, 256, 0, stream>>>(T, tmp, m, s);
    }
    k_w<<<dim3(m / 64, dim / 64), 256, 0, stream>>>(V, T, W, m, dim);
    k_q<<<dim3(dim / 64, dim / 64), 256, 0, stream>>>(W, V, Qt, m, dim);
    k_apply<<<dim3(dim / 128, n / 128), 256, 0, stream>>>(x, Qt, bias, out, n, dim);
}

// Round 2
// 295.908 us; speedup vs baseline: 1.4973x; 1.4973x over previous
//
#include <hip/hip_runtime.h>
#include <hip/hip_bf16.h>

typedef __attribute__((ext_vector_type(8))) short short8;
typedef __attribute__((ext_vector_type(4))) short s16x4;
typedef __attribute__((ext_vector_type(4))) float f32x4;

// fp32 -> bf16 bits, round-to-nearest-even
static __device__ inline short f2bf(float f) {
    unsigned u = __float_as_uint(f);
    unsigned r = (u + 0x7fffu + ((u >> 16) & 1u)) >> 16;
    return (short)r;
}
static __device__ inline float bf2f(short h) {
    return __uint_as_float(((unsigned)(unsigned short)h) << 16);
}

__global__ void k_zero(float* p, int n) {
    for (int i = blockIdx.x * blockDim.x + threadIdx.x; i < n; i += gridDim.x * blockDim.x)
        p[i] = 0.f;
}

// Normalize each row of vectors -> V (fp32)
__global__ __launch_bounds__(256) void k_normalize(const float* __restrict__ vec,
                                                   float* __restrict__ V, int dim) {
    int row = blockIdx.x;
    const float4* src = (const float4*)(vec + (size_t)row * dim);
    float4* dst = (float4*)(V + (size_t)row * dim);
    int nv4 = dim >> 2;
    float ss = 0.f;
    for (int i = threadIdx.x; i < nv4; i += blockDim.x) {
        float4 v = src[i];
        ss += v.x * v.x + v.y * v.y + v.z * v.z + v.w * v.w;
    }
    for (int off = 32; off; off >>= 1) ss += __shfl_down(ss, off, 64);
    __shared__ float ws_[4];
    int lane = threadIdx.x & 63, w = threadIdx.x >> 6;
    if (lane == 0) ws_[w] = ss;
    __syncthreads();
    float inv = 1.0f / sqrtf(ws_[0] + ws_[1] + ws_[2] + ws_[3]);
    for (int i = threadIdx.x; i < nv4; i += blockDim.x) {
        float4 v = src[i];
        v.x *= inv; v.y *= inv; v.z *= inv; v.w *= inv;
        dst[i] = v;
    }
}

// fp32 -> (hi, lo) bf16 split, elementwise
__global__ __launch_bounds__(256) void k_split(const float* __restrict__ X,
                                               short* __restrict__ Xh,
                                               short* __restrict__ Xl, int n4) {
    for (int i = blockIdx.x * blockDim.x + threadIdx.x; i < n4; i += gridDim.x * blockDim.x) {
        float4 v = ((const float4*)X)[i];
        float f[4] = {v.x, v.y, v.z, v.w};
        s16x4 h, l;
#pragma unroll
        for (int q = 0; q < 4; ++q) {
            h[q] = f2bf(f[q]);
            l[q] = f2bf(f[q] - bf2f(h[q]));
        }
        *(s16x4*)&Xh[(size_t)i * 4] = h;
        *(s16x4*)&Xl[(size_t)i * 4] = l;
    }
}

// fp32 -> bf16 (hi only), elementwise
__global__ __launch_bounds__(256) void k_cast(const float* __restrict__ X,
                                              short* __restrict__ Xh, int n4) {
    for (int i = blockIdx.x * blockDim.x + threadIdx.x; i < n4; i += gridDim.x * blockDim.x) {
        float4 v = ((const float4*)X)[i];
        float f[4] = {v.x, v.y, v.z, v.w};
        s16x4 h;
#pragma unroll
        for (int q = 0; q < 4; ++q) h[q] = f2bf(f[q]);
        *(s16x4*)&Xh[(size_t)i * 4] = h;
    }
}

// transpose + split: X (R x C, fp32) -> Xth, Xtl (C x R, bf16)
__global__ __launch_bounds__(256) void k_tsplit(const float* __restrict__ X,
                                                short* __restrict__ Xth,
                                                short* __restrict__ Xtl, int R, int C) {
    __shared__ float tile[32][33];
    int c0 = blockIdx.x * 32, r0 = blockIdx.y * 32;
    int t = threadIdx.x;
    int r = t >> 3, c4 = (t & 7) * 4;
    float4 v = *(const float4*)&X[(size_t)(r0 + r) * C + c0 + c4];
    tile[r][c4 + 0] = v.x; tile[r][c4 + 1] = v.y;
    tile[r][c4 + 2] = v.z; tile[r][c4 + 3] = v.w;
    __syncthreads();
    int rr = t >> 3, cc4 = (t & 7) * 4;
    s16x4 h, l;
#pragma unroll
    for (int q = 0; q < 4; ++q) {
        float f = tile[cc4 + q][rr];
        h[q] = f2bf(f);
        l[q] = f2bf(f - bf2f(h[q]));
    }
    *(s16x4*)&Xth[(size_t)(c0 + rr) * R + r0 + cc4] = h;
    *(s16x4*)&Xtl[(size_t)(c0 + rr) * R + r0 + cc4] = l;
}

// NT GEMM with split-bf16 operands: C[i][j] = sum_k A[i][k]*B[j][k]
// acc = Ah*Bh + Ah*Bl + Al*Bh (drops lo*lo: ~2^-18 relative).
// MODE 0: Cf[idx] = acc (fp32).  MODE 1: split-write Ch/Cl.  MODE 2: Ch = bf16(delta - acc).
template<int MODE>
__global__ __launch_bounds__(256) void k_nt64(
    const short* __restrict__ Ah, const short* __restrict__ Al,
    const short* __restrict__ Bh, const short* __restrict__ Bl,
    float* __restrict__ Cf, short* __restrict__ Ch, short* __restrict__ Cl,
    int K, int lda, int ldb, int ldc) {
    __shared__ short As[2][64 * 32];
    __shared__ short Bs[2][64 * 32];
    int i0 = blockIdx.y * 64, j0 = blockIdx.x * 64;
    int t = threadIdx.x, lane = t & 63, wave = t >> 6;
    int wr = wave >> 1, wc = wave & 1;
    int srow = t >> 2, soff = (t & 3) * 8;
    f32x4 acc[2][2] = {};
    for (int k0 = 0; k0 < K; k0 += 32) {
        __syncthreads();
        *(short8*)&As[0][srow * 32 + soff] = *(const short8*)&Ah[(size_t)(i0 + srow) * lda + k0 + soff];
        *(short8*)&As[1][srow * 32 + soff] = *(const short8*)&Al[(size_t)(i0 + srow) * lda + k0 + soff];
        *(short8*)&Bs[0][srow * 32 + soff] = *(const short8*)&Bh[(size_t)(j0 + srow) * ldb + k0 + soff];
        *(short8*)&Bs[1][srow * 32 + soff] = *(const short8*)&Bl[(size_t)(j0 + srow) * ldb + k0 + soff];
        __syncthreads();
        short8 ah[2], al2[2], bh[2], bl2[2];
#pragma unroll
        for (int i = 0; i < 2; ++i) {
            int ro = (wr * 32 + i * 16 + (lane & 15)) * 32 + (lane >> 4) * 8;
            ah[i] = *(const short8*)&As[0][ro];
            al2[i] = *(const short8*)&As[1][ro];
        }
#pragma unroll
        for (int j = 0; j < 2; ++j) {
            int ro = (wc * 32 + j * 16 + (lane & 15)) * 32 + (lane >> 4) * 8;
            bh[j] = *(const short8*)&Bs[0][ro];
            bl2[j] = *(const short8*)&Bs[1][ro];
        }
#pragma unroll
        for (int i = 0; i < 2; ++i)
#pragma unroll
            for (int j = 0; j < 2; ++j) {
                acc[i][j] = __builtin_amdgcn_mfma_f32_16x16x32_bf16(ah[i], bh[j], acc[i][j], 0, 0, 0);
                acc[i][j] = __builtin_amdgcn_mfma_f32_16x16x32_bf16(ah[i], bl2[j], acc[i][j], 0, 0, 0);
                acc[i][j] = __builtin_amdgcn_mfma_f32_16x16x32_bf16(al2[i], bh[j], acc[i][j], 0, 0, 0);
            }
    }
#pragma unroll
    for (int i = 0; i < 2; ++i)
#pragma unroll
        for (int j = 0; j < 2; ++j) {
            int row0 = i0 + wr * 32 + i * 16 + ((lane >> 4) << 2);
            int col = j0 + wc * 32 + j * 16 + (lane & 15);
#pragma unroll
            for (int r = 0; r < 4; ++r) {
                float v = acc[i][j][r];
                size_t idx = (size_t)(row0 + r) * ldc + col;
                if (MODE == 0) {
                    Cf[idx] = v;
                } else if (MODE == 1) {
                    short h = f2bf(v);
                    Ch[idx] = h;
                    Cl[idx] = f2bf(v - bf2f(h));
                } else {
                    Ch[idx] = f2bf((((row0 + r) == col) ? 1.f : 0.f) - v);
                }
            }
        }
}

// Invert 64x64 diagonal blocks of R = 0.5 I + striu(G) -> T (per-column back-substitution)
__global__ __launch_bounds__(64) void k_baseinv(const float* __restrict__ G,
                                                float* __restrict__ T, int m) {
    __shared__ float R[64 * 65];
    __shared__ float X[64 * 65];
    int b0 = blockIdx.x * 64;
    int c = threadIdx.x;
    for (int r = 0; r < 64; ++r) {
        R[r * 65 + c] = (r < c) ? G[(size_t)(b0 + r) * m + b0 + c] : (r == c ? 0.5f : 0.f);
        X[r * 65 + c] = (r == c) ? 2.f : 0.f;
    }
    __syncthreads();
    for (int r = 62; r >= 0; --r) {
        float s = 0.f;
        for (int i = r + 1; i < 64; ++i) s += R[r * 65 + i] * X[i * 65 + c];
        if (r < c) X[r * 65 + c] = -2.f * s;
    }
    __syncthreads();
    for (int r = 0; r < 64; ++r)
        T[(size_t)(b0 + r) * m + b0 + c] = X[r * 65 + c];
}

__device__ inline void st8(float* p, float4 a, float4 b) {
    p[0] = a.x; p[1] = a.y; p[2] = a.z; p[3] = a.w;
    p[4] = b.x; p[5] = b.y; p[6] = b.z; p[7] = b.w;
}

// tree level: tmp_p = G_B * Cinv
__global__ __launch_bounds__(256) void k_tree_a(const float* __restrict__ G,
                                                const float* __restrict__ T,
                                                float* __restrict__ tmp, int m, int s) {
    int p = blockIdx.z;
    int a0 = 2 * p * s, c0 = a0 + s;
    int r0t = blockIdx.y * 64, c0t = blockIdx.x * 64;
    __shared__ float As[64 * 33];
    __shared__ float Bs[32 * 65];
    int t = threadIdx.x, tx = t & 15, ty = t >> 4;
    float acc[4][4] = {};
    for (int k0 = 0; k0 < s; k0 += 32) {
        __syncthreads();
        {
            int r = t >> 2, cc = (t & 3) * 8;
            const float4* pa = (const float4*)(G + (size_t)(a0 + r0t + r) * m + c0 + k0 + cc);
            st8(&As[r * 33 + cc], pa[0], pa[1]);
        }
        {
            int r = t >> 3, cc = (t & 7) * 8;
            const float4* pb = (const float4*)(T + (size_t)(c0 + k0 + r) * m + c0 + c0t + cc);
            st8(&Bs[r * 65 + cc], pb[0], pb[1]);
        }
        __syncthreads();
#pragma unroll
        for (int kk = 0; kk < 32; ++kk) {
            float av[4], bv[4];
#pragma unroll
            for (int i = 0; i < 4; ++i) av[i] = As[(ty * 4 + i) * 33 + kk];
#pragma unroll
            for (int j = 0; j < 4; ++j) bv[j] = Bs[kk * 65 + tx * 4 + j];
#pragma unroll
            for (int i = 0; i < 4; ++i)
#pragma unroll
                for (int j = 0; j < 4; ++j) acc[i][j] += av[i] * bv[j];
        }
    }
#pragma unroll
    for (int i = 0; i < 4; ++i)
#pragma unroll
        for (int j = 0; j < 4; ++j)
            tmp[(size_t)p * s * s + (size_t)(r0t + ty * 4 + i) * s + c0t + tx * 4 + j] = acc[i][j];
}

// tree level: T[a0.., c0..] = -Ainv * tmp_p
__global__ __launch_bounds__(256) void k_tree_b(float* __restrict__ T,
                                                const float* __restrict__ tmp, int m, int s) {
    int p = blockIdx.z;
    int a0 = 2 * p * s, c0 = a0 + s;
    int r0t = blockIdx.y * 64, c0t = blockIdx.x * 64;
    __shared__ float As[64 * 33];
    __shared__ float Bs[32 * 65];
    int t = threadIdx.x, tx = t & 15, ty = t >> 4;
    float acc[4][4] = {};
    for (int k0 = 0; k0 < s; k0 += 32) {
        __syncthreads();
        {
            int r = t >> 2, cc = (t & 3) * 8;
            const float4* pa = (const float4*)(T + (size_t)(a0 + r0t + r) * m + a0 + k0 + cc);
            st8(&As[r * 33 + cc], pa[0], pa[1]);
        }
        {
            int r = t >> 3, cc = (t & 7) * 8;
            const float4* pb = (const float4*)(tmp + (size_t)p * s * s + (size_t)(k0 + r) * s + c0t + cc);
            st8(&Bs[r * 65 + cc], pb[0], pb[1]);
        }
        __syncthreads();
#pragma unroll
        for (int kk = 0; kk < 32; ++kk) {
            float av[4], bv[4];
#pragma unroll
            for (int i = 0; i < 4; ++i) av[i] = As[(ty * 4 + i) * 33 + kk];
#pragma unroll
            for (int j = 0; j < 4; ++j) bv[j] = Bs[kk * 65 + tx * 4 + j];
#pragma unroll
            for (int i = 0; i < 4; ++i)
#pragma unroll
                for (int j = 0; j < 4; ++j) acc[i][j] += av[i] * bv[j];
        }
    }
#pragma unroll
    for (int i = 0; i < 4; ++i)
#pragma unroll
        for (int j = 0; j < 4; ++j)
            T[(size_t)(a0 + r0t + ty * 4 + i) * m + c0 + c0t + tx * 4 + j] = -acc[i][j];
}

// out = xh * Qt^T + bias   (both operands already bf16; MFMA 16x16x32; 128x128 tiles)
__global__ __launch_bounds__(256) void k_apply2(const short* __restrict__ xh,
                                                const short* __restrict__ Qt,
                                                const float* __restrict__ bias,
                                                float* __restrict__ out, int dim) {
    __shared__ short As[128 * 32];
    __shared__ short Bs[128 * 32];
    int m0 = blockIdx.y * 128, n0 = blockIdx.x * 128;
    int t = threadIdx.x;
    int lane = t & 63, wave = t >> 6;
    int wr = wave >> 1, wc = wave & 1;
    int srow = t >> 1, soff = (t & 1) * 16;
    f32x4 acc[4][4] = {};
    for (int k0 = 0; k0 < dim; k0 += 32) {
        __syncthreads();
        {
            const short8* pa = (const short8*)&xh[(size_t)(m0 + srow) * dim + k0 + soff];
            short8 a0 = pa[0], a1 = pa[1];
            *(short8*)&As[srow * 32 + soff] = a0;
            *(short8*)&As[srow * 32 + soff + 8] = a1;
            const short8* pb = (const short8*)&Qt[(size_t)(n0 + srow) * dim + k0 + soff];
            short8 b0 = pb[0], b1 = pb[1];
            *(short8*)&Bs[srow * 32 + soff] = b0;
            *(short8*)&Bs[srow * 32 + soff + 8] = b1;
        }
        __syncthreads();
        short8 af[4], bf_[4];
#pragma unroll
        for (int i = 0; i < 4; ++i)
            af[i] = *(const short8*)&As[(wr * 64 + i * 16 + (lane & 15)) * 32 + (lane >> 4) * 8];
#pragma unroll
        for (int j = 0; j < 4; ++j)
            bf_[j] = *(const short8*)&Bs[(wc * 64 + j * 16 + (lane & 15)) * 32 + (lane >> 4) * 8];
#pragma unroll
        for (int i = 0; i < 4; ++i)
#pragma unroll
            for (int j = 0; j < 4; ++j)
                acc[i][j] = __builtin_amdgcn_mfma_f32_16x16x32_bf16(af[i], bf_[j], acc[i][j], 0, 0, 0);
    }
#pragma unroll
    for (int i = 0; i < 4; ++i)
#pragma unroll
        for (int j = 0; j < 4; ++j) {
            int row = m0 + wr * 64 + i * 16 + (lane >> 4) * 4;
            int col = n0 + wc * 64 + j * 16 + (lane & 15);
            float b = bias[col];
#pragma unroll
            for (int r = 0; r < 4; ++r)
                out[(size_t)(row + r) * dim + col] = acc[i][j][r] + b;
        }
}

extern "C" void kernel_launch(void* const* d_in, const int* in_sizes, int n_in,
                              void* d_out, int out_size, void* d_ws, size_t ws_size,
                              hipStream_t stream) {
    const float* x = (const float*)d_in[0];
    const float* vec = (const float*)d_in[1];
    const float* bias = (const float*)d_in[2];
    float* out = (float*)d_out;

    int dim = in_sizes[2];
    int m = in_sizes[1] / dim;
    int n = in_sizes[0] / dim;

    float* ws = (float*)d_ws;
    const size_t MD = (size_t)m * dim;   // 1M floats
    const size_t MM = (size_t)m * m;     // 1M floats
    // group 1 (all dead before xh is written):
    float* V = ws;                        // [0, MD)
    float* G = V + MD;                    // [MD, MD+MM)
    float* T = G + MM;
    float* tmp = T + MM;                  // MM/4
    short* Vh = (short*)(tmp + MM / 4);   // MD shorts = MD/2 floats
    short* Vl = Vh + MD;
    // group 2 (live across xh):
    float* g2 = (float*)(Vl + MD);
    short* Vth = (short*)g2;              // dim x m
    short* Vtl = Vth + MD;
    short* Tth = Vtl + MD;                // m x m
    short* Ttl = Tth + MM;
    short* Wh = Ttl + MM;                 // dim x m
    short* Wl = Wh + MD;
    short* Qt = Wl + MD;                  // dim x dim
    // xh aliases group 1 (n*dim shorts = 4M floats <= 4.25M floats of group 1)
    short* xh = (short*)ws;

    k_normalize<<<m, 256, 0, stream>>>(vec, V, dim);
    k_split<<<1024, 256, 0, stream>>>(V, Vh, Vl, (int)(MD / 4));
    k_tsplit<<<dim3(dim / 32, m / 32), 256, 0, stream>>>(V, Vth, Vtl, m, dim);

    // G = V * V^T (split MFMA, fp32 out)
    k_nt64<0><<<dim3(m / 64, m / 64), 256, 0, stream>>>(Vh, Vl, Vh, Vl, G, nullptr, nullptr,
                                                        dim, dim, dim, m);
    k_zero<<<256, 256, 0, stream>>>(T, m * m);
    k_baseinv<<<m / 64, 64, 0, stream>>>(G, T, m);
    for (int s = 64; s < m; s <<= 1) {
        dim3 g(s / 64, s / 64, m / (2 * s));
        k_tree_a<<<g, 256, 0, stream>>>(G, T, tmp, m, s);
        k_tree_b<<<g, 256, 0, stream>>>(T, tmp, m, s);
    }
    k_tsplit<<<dim3(m / 32, m / 32), 256, 0, stream>>>(T, Tth, Ttl, m, m);

    // W[d][k] = sum_j Vt[d][j] * Tt[k][j]  -> split bf16
    k_nt64<1><<<dim3(m / 64, dim / 64), 256, 0, stream>>>(Vth, Vtl, Tth, Ttl, nullptr, Wh, Wl,
                                                          m, m, m, m);
    // Qt[e][d] = delta - sum_k Vt[e][k] * W[d][k]
    k_nt64<2><<<dim3(dim / 64, dim / 64), 256, 0, stream>>>(Vth, Vtl, Wh, Wl, nullptr, Qt, nullptr,
                                                            m, m, m, dim);

    // xh = bf16(x); then out = xh * Qt^T + bias
    k_cast<<<2048, 256, 0, stream>>>(x, xh, (int)((size_t)n * dim / 4));
    k_apply2<<<dim3(dim / 128, n / 128), 256, 0, stream>>>(xh, Qt, bias, out, dim);
}

// Round 3
// 252.579 us; speedup vs baseline: 1.7542x; 1.1715x over previous
//
#include <hip/hip_runtime.h>
#include <hip/hip_bf16.h>

typedef __attribute__((ext_vector_type(8))) short short8;
typedef __attribute__((ext_vector_type(4))) short s16x4;
typedef __attribute__((ext_vector_type(4))) float f32x4;

// fp32 -> bf16 bits, round-to-nearest-even
static __device__ inline short f2bf(float f) {
    unsigned u = __float_as_uint(f);
    unsigned r = (u + 0x7fffu + ((u >> 16) & 1u)) >> 16;
    return (short)r;
}
static __device__ inline float bf2f(short h) {
    return __uint_as_float(((unsigned)(unsigned short)h) << 16);
}

__global__ void k_zero(float* p, int n) {
    for (int i = blockIdx.x * blockDim.x + threadIdx.x; i < n; i += gridDim.x * blockDim.x)
        p[i] = 0.f;
}

// Normalize each row of vectors -> V (fp32)
__global__ __launch_bounds__(256) void k_normalize(const float* __restrict__ vec,
                                                   float* __restrict__ V, int dim) {
    int row = blockIdx.x;
    const float4* src = (const float4*)(vec + (size_t)row * dim);
    float4* dst = (float4*)(V + (size_t)row * dim);
    int nv4 = dim >> 2;
    float ss = 0.f;
    for (int i = threadIdx.x; i < nv4; i += blockDim.x) {
        float4 v = src[i];
        ss += v.x * v.x + v.y * v.y + v.z * v.z + v.w * v.w;
    }
    for (int off = 32; off; off >>= 1) ss += __shfl_down(ss, off, 64);
    __shared__ float ws_[4];
    int lane = threadIdx.x & 63, w = threadIdx.x >> 6;
    if (lane == 0) ws_[w] = ss;
    __syncthreads();
    float inv = 1.0f / sqrtf(ws_[0] + ws_[1] + ws_[2] + ws_[3]);
    for (int i = threadIdx.x; i < nv4; i += blockDim.x) {
        float4 v = src[i];
        v.x *= inv; v.y *= inv; v.z *= inv; v.w *= inv;
        dst[i] = v;
    }
}

// fp32 -> (hi, lo) bf16 split, elementwise
__global__ __launch_bounds__(256) void k_split(const float* __restrict__ X,
                                               short* __restrict__ Xh,
                                               short* __restrict__ Xl, int n4) {
    for (int i = blockIdx.x * blockDim.x + threadIdx.x; i < n4; i += gridDim.x * blockDim.x) {
        float4 v = ((const float4*)X)[i];
        float f[4] = {v.x, v.y, v.z, v.w};
        s16x4 h, l;
#pragma unroll
        for (int q = 0; q < 4; ++q) {
            h[q] = f2bf(f[q]);
            l[q] = f2bf(f[q] - bf2f(h[q]));
        }
        *(s16x4*)&Xh[(size_t)i * 4] = h;
        *(s16x4*)&Xl[(size_t)i * 4] = l;
    }
}

// fp32 -> bf16 (hi only), elementwise
__global__ __launch_bounds__(256) void k_cast(const float* __restrict__ X,
                                              short* __restrict__ Xh, int n4) {
    for (int i = blockIdx.x * blockDim.x + threadIdx.x; i < n4; i += gridDim.x * blockDim.x) {
        float4 v = ((const float4*)X)[i];
        float f[4] = {v.x, v.y, v.z, v.w};
        s16x4 h;
#pragma unroll
        for (int q = 0; q < 4; ++q) h[q] = f2bf(f[q]);
        *(s16x4*)&Xh[(size_t)i * 4] = h;
    }
}

// transpose + split: X (R x C, fp32) -> Xth, Xtl (C x R, bf16)
__global__ __launch_bounds__(256) void k_tsplit(const float* __restrict__ X,
                                                short* __restrict__ Xth,
                                                short* __restrict__ Xtl, int R, int C) {
    __shared__ float tile[32][33];
    int c0 = blockIdx.x * 32, r0 = blockIdx.y * 32;
    int t = threadIdx.x;
    int r = t >> 3, c4 = (t & 7) * 4;
    float4 v = *(const float4*)&X[(size_t)(r0 + r) * C + c0 + c4];
    tile[r][c4 + 0] = v.x; tile[r][c4 + 1] = v.y;
    tile[r][c4 + 2] = v.z; tile[r][c4 + 3] = v.w;
    __syncthreads();
    int rr = t >> 3, cc4 = (t & 7) * 4;
    s16x4 h, l;
#pragma unroll
    for (int q = 0; q < 4; ++q) {
        float f = tile[cc4 + q][rr];
        h[q] = f2bf(f);
        l[q] = f2bf(f - bf2f(h[q]));
    }
    *(s16x4*)&Xth[(size_t)(c0 + rr) * R + r0 + cc4] = h;
    *(s16x4*)&Xtl[(size_t)(c0 + rr) * R + r0 + cc4] = l;
}

// NT GEMM with split-bf16 operands: C[i][j] = sum_k A[i][k]*B[j][k]
// acc = Ah*Bh + Ah*Bl + Al*Bh (drops lo*lo: ~2^-18 relative).
// MODE 0: Cf[idx] = acc (fp32).  MODE 1: split-write Ch/Cl.  MODE 2: Ch = bf16(delta - acc).
template<int MODE>
__global__ __launch_bounds__(256) void k_nt64(
    const short* __restrict__ Ah, const short* __restrict__ Al,
    const short* __restrict__ Bh, const short* __restrict__ Bl,
    float* __restrict__ Cf, short* __restrict__ Ch, short* __restrict__ Cl,
    int K, int lda, int ldb, int ldc) {
    __shared__ short As[2][64 * 32];
    __shared__ short Bs[2][64 * 32];
    int i0 = blockIdx.y * 64, j0 = blockIdx.x * 64;
    int t = threadIdx.x, lane = t & 63, wave = t >> 6;
    int wr = wave >> 1, wc = wave & 1;
    int srow = t >> 2, soff = (t & 3) * 8;
    f32x4 acc[2][2] = {};
    for (int k0 = 0; k0 < K; k0 += 32) {
        __syncthreads();
        *(short8*)&As[0][srow * 32 + soff] = *(const short8*)&Ah[(size_t)(i0 + srow) * lda + k0 + soff];
        *(short8*)&As[1][srow * 32 + soff] = *(const short8*)&Al[(size_t)(i0 + srow) * lda + k0 + soff];
        *(short8*)&Bs[0][srow * 32 + soff] = *(const short8*)&Bh[(size_t)(j0 + srow) * ldb + k0 + soff];
        *(short8*)&Bs[1][srow * 32 + soff] = *(const short8*)&Bl[(size_t)(j0 + srow) * ldb + k0 + soff];
        __syncthreads();
        short8 ah[2], al2[2], bh[2], bl2[2];
#pragma unroll
        for (int i = 0; i < 2; ++i) {
            int ro = (wr * 32 + i * 16 + (lane & 15)) * 32 + (lane >> 4) * 8;
            ah[i] = *(const short8*)&As[0][ro];
            al2[i] = *(const short8*)&As[1][ro];
        }
#pragma unroll
        for (int j = 0; j < 2; ++j) {
            int ro = (wc * 32 + j * 16 + (lane & 15)) * 32 + (lane >> 4) * 8;
            bh[j] = *(const short8*)&Bs[0][ro];
            bl2[j] = *(const short8*)&Bs[1][ro];
        }
#pragma unroll
        for (int i = 0; i < 2; ++i)
#pragma unroll
            for (int j = 0; j < 2; ++j) {
                acc[i][j] = __builtin_amdgcn_mfma_f32_16x16x32_bf16(ah[i], bh[j], acc[i][j], 0, 0, 0);
                acc[i][j] = __builtin_amdgcn_mfma_f32_16x16x32_bf16(ah[i], bl2[j], acc[i][j], 0, 0, 0);
                acc[i][j] = __builtin_amdgcn_mfma_f32_16x16x32_bf16(al2[i], bh[j], acc[i][j], 0, 0, 0);
            }
    }
#pragma unroll
    for (int i = 0; i < 2; ++i)
#pragma unroll
        for (int j = 0; j < 2; ++j) {
            int row0 = i0 + wr * 32 + i * 16 + ((lane >> 4) << 2);
            int col = j0 + wc * 32 + j * 16 + (lane & 15);
#pragma unroll
            for (int r = 0; r < 4; ++r) {
                float v = acc[i][j][r];
                size_t idx = (size_t)(row0 + r) * ldc + col;
                if (MODE == 0) {
                    Cf[idx] = v;
                } else if (MODE == 1) {
                    short h = f2bf(v);
                    Ch[idx] = h;
                    Cl[idx] = f2bf(v - bf2f(h));
                } else {
                    Ch[idx] = f2bf((((row0 + r) == col) ? 1.f : 0.f) - v);
                }
            }
        }
}

// Parallel inversion of 64x64 diagonal blocks of R = 0.5 I + striu(G).
// grid: 16 diag-blocks x 16 col-groups; 4 waves/block, one column per wave.
// Lane i holds X[i][c]; back-substitution top column-down with shfl reduce.
__global__ __launch_bounds__(256) void k_baseinv2(const float* __restrict__ G,
                                                  float* __restrict__ T, int m) {
    __shared__ float Rs[64 * 64];
    int d = blockIdx.x >> 4, g = blockIdx.x & 15;
    int b0 = d * 64;
    int t = threadIdx.x, lane = t & 63, wave = t >> 6;
    // stage raw G diag block (lower-triangle garbage multiplies zero lanes)
    {
        int r = t >> 2, c00 = (t & 3) * 16;
#pragma unroll
        for (int q = 0; q < 4; ++q)
            *(float4*)&Rs[r * 64 + c00 + q * 4] =
                *(const float4*)&G[(size_t)(b0 + r) * m + b0 + c00 + q * 4];
    }
    __syncthreads();
    int c = g * 4 + wave;
    float x = 0.f;
    for (int r = c; r >= 0; --r) {
        float prod = Rs[r * 64 + lane] * x;
        float s = prod;
#pragma unroll
        for (int off = 32; off; off >>= 1) s += __shfl_xor(s, off, 64);
        if (lane == r) x = ((r == c) ? 2.f : 0.f) - 2.f * s;
    }
    T[(size_t)(b0 + lane) * m + b0 + c] = x;
}

// Fused s=64 tree level: per pair p, T[a0..,c0..] = -Ainv * (G_B * Cinv).
// One block per pair; everything LDS-resident.
__global__ __launch_bounds__(256) void k_tree64(const float* __restrict__ G,
                                                float* __restrict__ T, int m) {
    __shared__ float Gb[64 * 65];
    __shared__ float Ai[64 * 65];
    __shared__ float Ci[64 * 64];
    __shared__ float Tm[64 * 64];
    int p = blockIdx.x;
    int a0 = p * 128, c0 = a0 + 64;
    int t = threadIdx.x;
    {
        int r = t >> 2, c00 = (t & 3) * 16;
#pragma unroll
        for (int q = 0; q < 4; ++q) {
            *(float4*)&Gb[r * 65 + c00 + q * 4] =
                *(const float4*)&G[(size_t)(a0 + r) * m + c0 + c00 + q * 4];
            *(float4*)&Ai[r * 65 + c00 + q * 4] =
                *(const float4*)&T[(size_t)(a0 + r) * m + a0 + c00 + q * 4];
            *(float4*)&Ci[r * 64 + c00 + q * 4] =
                *(const float4*)&T[(size_t)(c0 + r) * m + c0 + c00 + q * 4];
        }
    }
    __syncthreads();
    int tx = t & 15, ty = t >> 4;
    float acc[4][4] = {};
#pragma unroll 4
    for (int k = 0; k < 64; ++k) {
        float av[4], bv[4];
#pragma unroll
        for (int i = 0; i < 4; ++i) av[i] = Gb[(ty * 4 + i) * 65 + k];
#pragma unroll
        for (int j = 0; j < 4; ++j) bv[j] = Ci[k * 64 + tx * 4 + j];
#pragma unroll
        for (int i = 0; i < 4; ++i)
#pragma unroll
            for (int j = 0; j < 4; ++j) acc[i][j] += av[i] * bv[j];
    }
#pragma unroll
    for (int i = 0; i < 4; ++i)
#pragma unroll
        for (int j = 0; j < 4; ++j) Tm[(ty * 4 + i) * 64 + tx * 4 + j] = acc[i][j];
    __syncthreads();
    float acc2[4][4] = {};
#pragma unroll 4
    for (int k = 0; k < 64; ++k) {
        float av[4], bv[4];
#pragma unroll
        for (int i = 0; i < 4; ++i) av[i] = Ai[(ty * 4 + i) * 65 + k];
#pragma unroll
        for (int j = 0; j < 4; ++j) bv[j] = Tm[k * 64 + tx * 4 + j];
#pragma unroll
        for (int i = 0; i < 4; ++i)
#pragma unroll
            for (int j = 0; j < 4; ++j) acc2[i][j] += av[i] * bv[j];
    }
#pragma unroll
    for (int i = 0; i < 4; ++i)
#pragma unroll
        for (int j = 0; j < 4; ++j)
            T[(size_t)(a0 + ty * 4 + i) * m + c0 + tx * 4 + j] = -acc2[i][j];
}

__device__ inline void st8(float* p, float4 a, float4 b) {
    p[0] = a.x; p[1] = a.y; p[2] = a.z; p[3] = a.w;
    p[4] = b.x; p[5] = b.y; p[6] = b.z; p[7] = b.w;
}

// tree level: tmp_p = G_B * Cinv
__global__ __launch_bounds__(256) void k_tree_a(const float* __restrict__ G,
                                                const float* __restrict__ T,
                                                float* __restrict__ tmp, int m, int s) {
    int p = blockIdx.z;
    int a0 = 2 * p * s, c0 = a0 + s;
    int r0t = blockIdx.y * 64, c0t = blockIdx.x * 64;
    __shared__ float As[64 * 33];
    __shared__ float Bs[32 * 65];
    int t = threadIdx.x, tx = t & 15, ty = t >> 4;
    float acc[4][4] = {};
    for (int k0 = 0; k0 < s; k0 += 32) {
        __syncthreads();
        {
            int r = t >> 2, cc = (t & 3) * 8;
            const float4* pa = (const float4*)(G + (size_t)(a0 + r0t + r) * m + c0 + k0 + cc);
            st8(&As[r * 33 + cc], pa[0], pa[1]);
        }
        {
            int r = t >> 3, cc = (t & 7) * 8;
            const float4* pb = (const float4*)(T + (size_t)(c0 + k0 + r) * m + c0 + c0t + cc);
            st8(&Bs[r * 65 + cc], pb[0], pb[1]);
        }
        __syncthreads();
#pragma unroll
        for (int kk = 0; kk < 32; ++kk) {
            float av[4], bv[4];
#pragma unroll
            for (int i = 0; i < 4; ++i) av[i] = As[(ty * 4 + i) * 33 + kk];
#pragma unroll
            for (int j = 0; j < 4; ++j) bv[j] = Bs[kk * 65 + tx * 4 + j];
#pragma unroll
            for (int i = 0; i < 4; ++i)
#pragma unroll
                for (int j = 0; j < 4; ++j) acc[i][j] += av[i] * bv[j];
        }
    }
#pragma unroll
    for (int i = 0; i < 4; ++i)
#pragma unroll
        for (int j = 0; j < 4; ++j)
            tmp[(size_t)p * s * s + (size_t)(r0t + ty * 4 + i) * s + c0t + tx * 4 + j] = acc[i][j];
}

// tree level: T[a0.., c0..] = -Ainv * tmp_p
__global__ __launch_bounds__(256) void k_tree_b(float* __restrict__ T,
                                                const float* __restrict__ tmp, int m, int s) {
    int p = blockIdx.z;
    int a0 = 2 * p * s, c0 = a0 + s;
    int r0t = blockIdx.y * 64, c0t = blockIdx.x * 64;
    __shared__ float As[64 * 33];
    __shared__ float Bs[32 * 65];
    int t = threadIdx.x, tx = t & 15, ty = t >> 4;
    float acc[4][4] = {};
    for (int k0 = 0; k0 < s; k0 += 32) {
        __syncthreads();
        {
            int r = t >> 2, cc = (t & 3) * 8;
            const float4* pa = (const float4*)(T + (size_t)(a0 + r0t + r) * m + a0 + k0 + cc);
            st8(&As[r * 33 + cc], pa[0], pa[1]);
        }
        {
            int r = t >> 3, cc = (t & 7) * 8;
            const float4* pb = (const float4*)(tmp + (size_t)p * s * s + (size_t)(k0 + r) * s + c0t + cc);
            st8(&Bs[r * 65 + cc], pb[0], pb[1]);
        }
        __syncthreads();
#pragma unroll
        for (int kk = 0; kk < 32; ++kk) {
            float av[4], bv[4];
#pragma unroll
            for (int i = 0; i < 4; ++i) av[i] = As[(ty * 4 + i) * 33 + kk];
#pragma unroll
            for (int j = 0; j < 4; ++j) bv[j] = Bs[kk * 65 + tx * 4 + j];
#pragma unroll
            for (int i = 0; i < 4; ++i)
#pragma unroll
                for (int j = 0; j < 4; ++j) acc[i][j] += av[i] * bv[j];
        }
    }
#pragma unroll
    for (int i = 0; i < 4; ++i)
#pragma unroll
        for (int j = 0; j < 4; ++j)
            T[(size_t)(a0 + r0t + ty * 4 + i) * m + c0 + c0t + tx * 4 + j] = -acc[i][j];
}

// out = xh * Qt^T + bias.  m97 structure: 128x128 tile, BK=64,
// global_load_lds width-16 staging, 4 waves, 4x4 16x16 fragments per wave.
__global__ __launch_bounds__(256) void k_apply3(const short* __restrict__ xh,
                                                const short* __restrict__ Qt,
                                                const float* __restrict__ bias,
                                                float* __restrict__ out, int dim) {
    __shared__ short As[128 * 64];  // [row][k], 16 KB
    __shared__ short Bs[128 * 64];
    int m0 = blockIdx.y * 128, n0 = blockIdx.x * 128;
    int t = threadIdx.x, lane = t & 63, wave = t >> 6;
    int wr = wave >> 1, wc = wave & 1;
    int sr = lane >> 3;           // row within 8-row group
    int sc = (lane & 7) * 8;      // bf16-element offset within 64-wide K slice
    f32x4 acc[4][4] = {};
    for (int k0 = 0; k0 < dim; k0 += 64) {
        __syncthreads();
#pragma unroll
        for (int q = 0; q < 4; ++q) {
            int rg = wave * 4 + q;          // 8-row group 0..15
            int row = rg * 8 + sr;
            const short* gA = &xh[(size_t)(m0 + row) * dim + k0 + sc];
            const short* gB = &Qt[(size_t)(n0 + row) * dim + k0 + sc];
            __builtin_amdgcn_global_load_lds(
                (const __attribute__((address_space(1))) void*)gA,
                (__attribute__((address_space(3))) void*)&As[rg * 8 * 64], 16, 0, 0);
            __builtin_amdgcn_global_load_lds(
                (const __attribute__((address_space(1))) void*)gB,
                (__attribute__((address_space(3))) void*)&Bs[rg * 8 * 64], 16, 0, 0);
        }
        __syncthreads();
#pragma unroll
        for (int kk = 0; kk < 2; ++kk) {
            short8 af[4], bf_[4];
#pragma unroll
            for (int i = 0; i < 4; ++i)
                af[i] = *(const short8*)&As[(wr * 64 + i * 16 + (lane & 15)) * 64 + kk * 32 + (lane >> 4) * 8];
#pragma unroll
            for (int j = 0; j < 4; ++j)
                bf_[j] = *(const short8*)&Bs[(wc * 64 + j * 16 + (lane & 15)) * 64 + kk * 32 + (lane >> 4) * 8];
#pragma unroll
            for (int i = 0; i < 4; ++i)
#pragma unroll
                for (int j = 0; j < 4; ++j)
                    acc[i][j] = __builtin_amdgcn_mfma_f32_16x16x32_bf16(af[i], bf_[j], acc[i][j], 0, 0, 0);
        }
    }
#pragma unroll
    for (int i = 0; i < 4; ++i)
#pragma unroll
        for (int j = 0; j < 4; ++j) {
            int row = m0 + wr * 64 + i * 16 + (lane >> 4) * 4;
            int col = n0 + wc * 64 + j * 16 + (lane & 15);
            float b = bias[col];
#pragma unroll
            for (int r = 0; r < 4; ++r)
                out[(size_t)(row + r) * dim + col] = acc[i][j][r] + b;
        }
}

extern "C" void kernel_launch(void* const* d_in, const int* in_sizes, int n_in,
                              void* d_out, int out_size, void* d_ws, size_t ws_size,
                              hipStream_t stream) {
    const float* x = (const float*)d_in[0];
    const float* vec = (const float*)d_in[1];
    const float* bias = (const float*)d_in[2];
    float* out = (float*)d_out;

    int dim = in_sizes[2];
    int m = in_sizes[1] / dim;
    int n = in_sizes[0] / dim;

    float* ws = (float*)d_ws;
    const size_t MD = (size_t)m * dim;   // 1M floats
    const size_t MM = (size_t)m * m;     // 1M floats
    // group 1 (all dead before xh is written):
    float* V = ws;
    float* G = V + MD;
    float* T = G + MM;
    float* tmp = T + MM;                  // MM/4
    short* Vh = (short*)(tmp + MM / 4);
    short* Vl = Vh + MD;
    // group 2 (live across xh):
    float* g2 = (float*)(Vl + MD);
    short* Vth = (short*)g2;
    short* Vtl = Vth + MD;
    short* Tth = Vtl + MD;
    short* Ttl = Tth + MM;
    short* Wh = Ttl + MM;
    short* Wl = Wh + MD;
    short* Qt = Wl + MD;
    // xh aliases group 1
    short* xh = (short*)ws;

    k_normalize<<<m, 256, 0, stream>>>(vec, V, dim);
    k_split<<<1024, 256, 0, stream>>>(V, Vh, Vl, (int)(MD / 4));
    k_tsplit<<<dim3(dim / 32, m / 32), 256, 0, stream>>>(V, Vth, Vtl, m, dim);

    // G = V * V^T (split MFMA, fp32 out)
    k_nt64<0><<<dim3(m / 64, m / 64), 256, 0, stream>>>(Vh, Vl, Vh, Vl, G, nullptr, nullptr,
                                                        dim, dim, dim, m);
    k_zero<<<256, 256, 0, stream>>>(T, m * m);
    k_baseinv2<<<(m / 64) * 16, 256, 0, stream>>>(G, T, m);
    k_tree64<<<m / 128, 256, 0, stream>>>(G, T, m);
    for (int s = 128; s < m; s <<= 1) {
        dim3 g(s / 64, s / 64, m / (2 * s));
        k_tree_a<<<g, 256, 0, stream>>>(G, T, tmp, m, s);
        k_tree_b<<<g, 256, 0, stream>>>(T, tmp, m, s);
    }
    k_tsplit<<<dim3(m / 32, m / 32), 256, 0, stream>>>(T, Tth, Ttl, m, m);

    // W[d][k] = sum_j Vt[d][j] * Tt[k][j]  -> split bf16
    k_nt64<1><<<dim3(m / 64, dim / 64), 256, 0, stream>>>(Vth, Vtl, Tth, Ttl, nullptr, Wh, Wl,
                                                          m, m, m, m);
    // Qt[e][d] = delta - sum_k Vt[e][k] * W[d][k]
    k_nt64<2><<<dim3(dim / 64, dim / 64), 256, 0, stream>>>(Vth, Vtl, Wh, Wl, nullptr, Qt, nullptr,
                                                            m, m, m, dim);

    // xh = bf16(x); then out = xh * Qt^T + bias
    k_cast<<<2048, 256, 0, stream>>>(x, xh, (int)((size_t)n * dim / 4));
    k_apply3<<<dim3(dim / 128, n / 128), 256, 0, stream>>>(xh, Qt, bias, out, dim);
}

// Round 4
// 178.858 us; speedup vs baseline: 2.4772x; 1.4122x over previous
//
#include <hip/hip_runtime.h>
#include <hip/hip_bf16.h>

typedef __attribute__((ext_vector_type(8))) short short8;
typedef __attribute__((ext_vector_type(4))) short s16x4;
typedef __attribute__((ext_vector_type(4))) float f32x4;

// fp32 -> bf16 bits, round-to-nearest-even
static __device__ inline short f2bf(float f) {
    unsigned u = __float_as_uint(f);
    unsigned r = (u + 0x7fffu + ((u >> 16) & 1u)) >> 16;
    return (short)r;
}
static __device__ inline float bf2f(short h) {
    return __uint_as_float(((unsigned)(unsigned short)h) << 16);
}

// Swizzled LDS short-offset for 32-short (64B) rows; 16B slot in 0..3.
// slot' = slot ^ ((row>>1)&3) spreads 8 consecutive rows over 8 bank-groups.
static __device__ inline int swz32(int row, int slot) {
    return row * 32 + ((slot ^ ((row >> 1) & 3)) << 3);
}
// For 64-short (128B) rows; 16B slot in 0..7.
static __device__ inline int swz64(int row, int slot) {
    return row * 64 + ((slot ^ (row & 7)) << 3);
}

// Normalize each row of vectors -> V (fp32)
__global__ __launch_bounds__(256) void k_normalize(const float* __restrict__ vec,
                                                   float* __restrict__ V, int dim) {
    int row = blockIdx.x;
    const float4* src = (const float4*)(vec + (size_t)row * dim);
    float4* dst = (float4*)(V + (size_t)row * dim);
    int nv4 = dim >> 2;
    float ss = 0.f;
    for (int i = threadIdx.x; i < nv4; i += blockDim.x) {
        float4 v = src[i];
        ss += v.x * v.x + v.y * v.y + v.z * v.z + v.w * v.w;
    }
    for (int off = 32; off; off >>= 1) ss += __shfl_down(ss, off, 64);
    __shared__ float ws_[4];
    int lane = threadIdx.x & 63, w = threadIdx.x >> 6;
    if (lane == 0) ws_[w] = ss;
    __syncthreads();
    float inv = 1.0f / sqrtf(ws_[0] + ws_[1] + ws_[2] + ws_[3]);
    for (int i = threadIdx.x; i < nv4; i += blockDim.x) {
        float4 v = src[i];
        v.x *= inv; v.y *= inv; v.z *= inv; v.w *= inv;
        dst[i] = v;
    }
}

// fp32 -> (hi, lo) bf16 split, elementwise
__global__ __launch_bounds__(256) void k_split(const float* __restrict__ X,
                                               short* __restrict__ Xh,
                                               short* __restrict__ Xl, int n4) {
    for (int i = blockIdx.x * blockDim.x + threadIdx.x; i < n4; i += gridDim.x * blockDim.x) {
        float4 v = ((const float4*)X)[i];
        float f[4] = {v.x, v.y, v.z, v.w};
        s16x4 h, l;
#pragma unroll
        for (int q = 0; q < 4; ++q) {
            h[q] = f2bf(f[q]);
            l[q] = f2bf(f[q] - bf2f(h[q]));
        }
        *(s16x4*)&Xh[(size_t)i * 4] = h;
        *(s16x4*)&Xl[(size_t)i * 4] = l;
    }
}

// fp32 -> bf16 (hi only), elementwise
__global__ __launch_bounds__(256) void k_cast(const float* __restrict__ X,
                                              short* __restrict__ Xh, int n4) {
    for (int i = blockIdx.x * blockDim.x + threadIdx.x; i < n4; i += gridDim.x * blockDim.x) {
        float4 v = ((const float4*)X)[i];
        float f[4] = {v.x, v.y, v.z, v.w};
        s16x4 h;
#pragma unroll
        for (int q = 0; q < 4; ++q) h[q] = f2bf(f[q]);
        *(s16x4*)&Xh[(size_t)i * 4] = h;
    }
}

// transpose + split: X (R x C, fp32) -> Xth, Xtl (C x R, bf16)
__global__ __launch_bounds__(256) void k_tsplit(const float* __restrict__ X,
                                                short* __restrict__ Xth,
                                                short* __restrict__ Xtl, int R, int C) {
    __shared__ float tile[32][33];
    int c0 = blockIdx.x * 32, r0 = blockIdx.y * 32;
    int t = threadIdx.x;
    int r = t >> 3, c4 = (t & 7) * 4;
    float4 v = *(const float4*)&X[(size_t)(r0 + r) * C + c0 + c4];
    tile[r][c4 + 0] = v.x; tile[r][c4 + 1] = v.y;
    tile[r][c4 + 2] = v.z; tile[r][c4 + 3] = v.w;
    __syncthreads();
    int rr = t >> 3, cc4 = (t & 7) * 4;
    s16x4 h, l;
#pragma unroll
    for (int q = 0; q < 4; ++q) {
        float f = tile[cc4 + q][rr];
        h[q] = f2bf(f);
        l[q] = f2bf(f - bf2f(h[q]));
    }
    *(s16x4*)&Xth[(size_t)(c0 + rr) * R + r0 + cc4] = h;
    *(s16x4*)&Xtl[(size_t)(c0 + rr) * R + r0 + cc4] = l;
}

// NT GEMM with split-bf16 operands: C[i][j] = sum_k A[i][k]*B[j][k]
// acc = Ah*Bh + Ah*Bl + Al*Bh (drops lo*lo).
// MODE 1: split-write Ch/Cl.  MODE 2: Ch = bf16(delta - acc).  MODE 3: Cf + Ch/Cl.
// TRI 0: full K.  TRI 1: K-bound = j0+64 (B rows triangular).  TRI 2: skip blocks j0<i0.
template<int MODE, int TRI>
__global__ __launch_bounds__(256) void k_nt64(
    const short* __restrict__ Ah, const short* __restrict__ Al,
    const short* __restrict__ Bh, const short* __restrict__ Bl,
    float* __restrict__ Cf, short* __restrict__ Ch, short* __restrict__ Cl,
    int K, int lda, int ldb, int ldc) {
    __shared__ short As[2][64 * 32];
    __shared__ short Bs[2][64 * 32];
    int i0 = blockIdx.y * 64, j0 = blockIdx.x * 64;
    if (TRI == 2 && j0 < i0) return;
    int KE = (TRI == 1) ? (j0 + 64) : K;
    int t = threadIdx.x, lane = t & 63, wave = t >> 6;
    int wr = wave >> 1, wc = wave & 1;
    int srow = t >> 2, slot = t & 3;
    int sofs = swz32(srow, slot);
    int gofs = slot * 8;
    f32x4 acc[2][2] = {};
    for (int k0 = 0; k0 < KE; k0 += 32) {
        __syncthreads();
        *(short8*)&As[0][sofs] = *(const short8*)&Ah[(size_t)(i0 + srow) * lda + k0 + gofs];
        *(short8*)&As[1][sofs] = *(const short8*)&Al[(size_t)(i0 + srow) * lda + k0 + gofs];
        *(short8*)&Bs[0][sofs] = *(const short8*)&Bh[(size_t)(j0 + srow) * ldb + k0 + gofs];
        *(short8*)&Bs[1][sofs] = *(const short8*)&Bl[(size_t)(j0 + srow) * ldb + k0 + gofs];
        __syncthreads();
        int g = lane >> 4;
        short8 ah[2], al2[2], bh[2], bl2[2];
#pragma unroll
        for (int i = 0; i < 2; ++i) {
            int ro = swz32(wr * 32 + i * 16 + (lane & 15), g);
            ah[i] = *(const short8*)&As[0][ro];
            al2[i] = *(const short8*)&As[1][ro];
        }
#pragma unroll
        for (int j = 0; j < 2; ++j) {
            int ro = swz32(wc * 32 + j * 16 + (lane & 15), g);
            bh[j] = *(const short8*)&Bs[0][ro];
            bl2[j] = *(const short8*)&Bs[1][ro];
        }
#pragma unroll
        for (int i = 0; i < 2; ++i)
#pragma unroll
            for (int j = 0; j < 2; ++j) {
                acc[i][j] = __builtin_amdgcn_mfma_f32_16x16x32_bf16(ah[i], bh[j], acc[i][j], 0, 0, 0);
                acc[i][j] = __builtin_amdgcn_mfma_f32_16x16x32_bf16(ah[i], bl2[j], acc[i][j], 0, 0, 0);
                acc[i][j] = __builtin_amdgcn_mfma_f32_16x16x32_bf16(al2[i], bh[j], acc[i][j], 0, 0, 0);
            }
    }
#pragma unroll
    for (int i = 0; i < 2; ++i)
#pragma unroll
        for (int j = 0; j < 2; ++j) {
            int row0 = i0 + wr * 32 + i * 16 + ((lane >> 4) << 2);
            int col = j0 + wc * 32 + j * 16 + (lane & 15);
#pragma unroll
            for (int r = 0; r < 4; ++r) {
                float v = acc[i][j][r];
                size_t idx = (size_t)(row0 + r) * ldc + col;
                if (MODE == 2) {
                    Ch[idx] = f2bf((((row0 + r) == col) ? 1.f : 0.f) - v);
                } else {
                    short h = f2bf(v);
                    short l = f2bf(v - bf2f(h));
                    Ch[idx] = h;
                    Cl[idx] = l;
                    if (MODE == 3) Cf[idx] = v;
                }
            }
        }
}

// Parallel inversion of 64x64 diagonal blocks of R = 0.5 I + striu(G).
// grid: (m/64) diag-blocks x 16 col-groups; 4 waves/block, one column per wave.
// Writes split row-major (Th/Tl) and transposed (Tth/Ttl).
__global__ __launch_bounds__(256) void k_baseinv2(const float* __restrict__ G,
                                                  short* __restrict__ Th, short* __restrict__ Tl,
                                                  short* __restrict__ Tth, short* __restrict__ Ttl,
                                                  int m) {
    __shared__ float Rs[64 * 64];
    int d = blockIdx.x >> 4, g = blockIdx.x & 15;
    int b0 = d * 64;
    int t = threadIdx.x, lane = t & 63, wave = t >> 6;
    {
        int r = t >> 2, c00 = (t & 3) * 16;
#pragma unroll
        for (int q = 0; q < 4; ++q)
            *(float4*)&Rs[r * 64 + c00 + q * 4] =
                *(const float4*)&G[(size_t)(b0 + r) * m + b0 + c00 + q * 4];
    }
    __syncthreads();
    int c = g * 4 + wave;
    float x = 0.f;
    for (int r = c; r >= 0; --r) {
        float prod = Rs[r * 64 + lane] * x;
        float s = prod;
#pragma unroll
        for (int off = 32; off; off >>= 1) s += __shfl_xor(s, off, 64);
        if (lane == r) x = ((r == c) ? 2.f : 0.f) - 2.f * s;
    }
    short h = f2bf(x);
    short l = f2bf(x - bf2f(h));
    Th[(size_t)(b0 + lane) * m + b0 + c] = h;
    Tl[(size_t)(b0 + lane) * m + b0 + c] = l;
    Tth[(size_t)(b0 + c) * m + b0 + lane] = h;
    Ttl[(size_t)(b0 + c) * m + b0 + lane] = l;
}

// Tree-level block GEMMs on split operands (NT MFMA, triangular K-bounds).
// PHASE 1: tmp^T = (G_B * Cinv)^T      A=Gh/Gl, B=Tth/Ttl, out C1 = tmpth/tmptl
//          (K bound: k < ct+64, Cinv upper-tri)
// PHASE 2: T_AB = -Ainv * tmp          A=Th/Tl, B=tmpth/tmptl,
//          out C1 = Th/Tl (row-major), C2 = Tth/Ttl (transposed)
//          (K bound: k >= r0, Ainv upper-tri)
template<int PHASE>
__global__ __launch_bounds__(256) void k_trimm(
    const short* __restrict__ Ah, const short* __restrict__ Al,
    const short* __restrict__ Bh, const short* __restrict__ Bl,
    short* __restrict__ C1h, short* __restrict__ C1l,
    short* __restrict__ C2h, short* __restrict__ C2l,
    int m, int s) {
    __shared__ short As[2][64 * 32];
    __shared__ short Bs[2][64 * 32];
    int p = blockIdx.z;
    int a0 = 2 * p * s, c0 = a0 + s;
    int r0 = blockIdx.y * 64, ct = blockIdx.x * 64;
    int KS = (PHASE == 1) ? 0 : r0;
    int KE = (PHASE == 1) ? (ct + 64) : s;
    size_t tbase = (size_t)p * s * s;
    int t = threadIdx.x, lane = t & 63, wave = t >> 6;
    int wr = wave >> 1, wc = wave & 1;
    int srow = t >> 2, slot = t & 3;
    int sofs = swz32(srow, slot);
    int gofs = slot * 8;
    f32x4 acc[2][2] = {};
    for (int k0 = KS; k0 < KE; k0 += 32) {
        __syncthreads();
        if (PHASE == 1) {
            *(short8*)&As[0][sofs] = *(const short8*)&Ah[(size_t)(a0 + r0 + srow) * m + c0 + k0 + gofs];
            *(short8*)&As[1][sofs] = *(const short8*)&Al[(size_t)(a0 + r0 + srow) * m + c0 + k0 + gofs];
            *(short8*)&Bs[0][sofs] = *(const short8*)&Bh[(size_t)(c0 + ct + srow) * m + c0 + k0 + gofs];
            *(short8*)&Bs[1][sofs] = *(const short8*)&Bl[(size_t)(c0 + ct + srow) * m + c0 + k0 + gofs];
        } else {
            *(short8*)&As[0][sofs] = *(const short8*)&Ah[(size_t)(a0 + r0 + srow) * m + a0 + k0 + gofs];
            *(short8*)&As[1][sofs] = *(const short8*)&Al[(size_t)(a0 + r0 + srow) * m + a0 + k0 + gofs];
            *(short8*)&Bs[0][sofs] = *(const short8*)&Bh[tbase + (size_t)(ct + srow) * s + k0 + gofs];
            *(short8*)&Bs[1][sofs] = *(const short8*)&Bl[tbase + (size_t)(ct + srow) * s + k0 + gofs];
        }
        __syncthreads();
        int g = lane >> 4;
        short8 ah[2], al2[2], bh[2], bl2[2];
#pragma unroll
        for (int i = 0; i < 2; ++i) {
            int ro = swz32(wr * 32 + i * 16 + (lane & 15), g);
            ah[i] = *(const short8*)&As[0][ro];
            al2[i] = *(const short8*)&As[1][ro];
        }
#pragma unroll
        for (int j = 0; j < 2; ++j) {
            int ro = swz32(wc * 32 + j * 16 + (lane & 15), g);
            bh[j] = *(const short8*)&Bs[0][ro];
            bl2[j] = *(const short8*)&Bs[1][ro];
        }
#pragma unroll
        for (int i = 0; i < 2; ++i)
#pragma unroll
            for (int j = 0; j < 2; ++j) {
                acc[i][j] = __builtin_amdgcn_mfma_f32_16x16x32_bf16(ah[i], bh[j], acc[i][j], 0, 0, 0);
                acc[i][j] = __builtin_amdgcn_mfma_f32_16x16x32_bf16(ah[i], bl2[j], acc[i][j], 0, 0, 0);
                acc[i][j] = __builtin_amdgcn_mfma_f32_16x16x32_bf16(al2[i], bh[j], acc[i][j], 0, 0, 0);
            }
    }
#pragma unroll
    for (int i = 0; i < 2; ++i)
#pragma unroll
        for (int j = 0; j < 2; ++j) {
            int row0 = r0 + wr * 32 + i * 16 + ((lane >> 4) << 2);
            int col = ct + wc * 32 + j * 16 + (lane & 15);
#pragma unroll
            for (int r = 0; r < 4; ++r) {
                if (PHASE == 1) {
                    float v = acc[i][j][r];
                    short h = f2bf(v);
                    short l = f2bf(v - bf2f(h));
                    size_t idx = tbase + (size_t)col * s + row0 + r;
                    C1h[idx] = h;
                    C1l[idx] = l;
                } else {
                    float v = -acc[i][j][r];
                    short h = f2bf(v);
                    short l = f2bf(v - bf2f(h));
                    int R = a0 + row0 + r, Cc = c0 + col;
                    C1h[(size_t)R * m + Cc] = h;
                    C1l[(size_t)R * m + Cc] = l;
                    C2h[(size_t)Cc * m + R] = h;
                    C2l[(size_t)Cc * m + R] = l;
                }
            }
        }
}

// out = xh * Qt^T + bias.  128x128 tile, BK=64, global_load_lds width-16 with
// pre-swizzled source (st-style XOR on 16B slots), swizzled ds_read.
__global__ __launch_bounds__(256) void k_apply3(const short* __restrict__ xh,
                                                const short* __restrict__ Qt,
                                                const float* __restrict__ bias,
                                                float* __restrict__ out, int dim) {
    __shared__ short As[128 * 64];  // 16 KB, linear dest (rule 21)
    __shared__ short Bs[128 * 64];
    int m0 = blockIdx.y * 128, n0 = blockIdx.x * 128;
    int t = threadIdx.x, lane = t & 63, wave = t >> 6;
    int wr = wave >> 1, wc = wave & 1;
    int sr = lane >> 3;               // row within 8-row group
    int sslot = (lane & 7) ^ (sr & 7);  // pre-swizzled source 16B slot
    f32x4 acc[4][4] = {};
    for (int k0 = 0; k0 < dim; k0 += 64) {
        __syncthreads();
#pragma unroll
        for (int q = 0; q < 4; ++q) {
            int rg = wave * 4 + q;          // 8-row group 0..15
            int row = rg * 8 + sr;
            const short* gA = &xh[(size_t)(m0 + row) * dim + k0 + sslot * 8];
            const short* gB = &Qt[(size_t)(n0 + row) * dim + k0 + sslot * 8];
            __builtin_amdgcn_global_load_lds(
                (const __attribute__((address_space(1))) void*)gA,
                (__attribute__((address_space(3))) void*)&As[rg * 8 * 64], 16, 0, 0);
            __builtin_amdgcn_global_load_lds(
                (const __attribute__((address_space(1))) void*)gB,
                (__attribute__((address_space(3))) void*)&Bs[rg * 8 * 64], 16, 0, 0);
        }
        __syncthreads();
#pragma unroll
        for (int kk = 0; kk < 2; ++kk) {
            int g = kk * 4 + (lane >> 4);   // 16B slot 0..7
            short8 af[4], bf_[4];
#pragma unroll
            for (int i = 0; i < 4; ++i)
                af[i] = *(const short8*)&As[swz64(wr * 64 + i * 16 + (lane & 15), g)];
#pragma unroll
            for (int j = 0; j < 4; ++j)
                bf_[j] = *(const short8*)&Bs[swz64(wc * 64 + j * 16 + (lane & 15), g)];
#pragma unroll
            for (int i = 0; i < 4; ++i)
#pragma unroll
                for (int j = 0; j < 4; ++j)
                    acc[i][j] = __builtin_amdgcn_mfma_f32_16x16x32_bf16(af[i], bf_[j], acc[i][j], 0, 0, 0);
        }
    }
#pragma unroll
    for (int i = 0; i < 4; ++i)
#pragma unroll
        for (int j = 0; j < 4; ++j) {
            int row = m0 + wr * 64 + i * 16 + (lane >> 4) * 4;
            int col = n0 + wc * 64 + j * 16 + (lane & 15);
            float b = bias[col];
#pragma unroll
            for (int r = 0; r < 4; ++r)
                out[(size_t)(row + r) * dim + col] = acc[i][j][r] + b;
        }
}

extern "C" void kernel_launch(void* const* d_in, const int* in_sizes, int n_in,
                              void* d_out, int out_size, void* d_ws, size_t ws_size,
                              hipStream_t stream) {
    const float* x = (const float*)d_in[0];
    const float* vec = (const float*)d_in[1];
    const float* bias = (const float*)d_in[2];
    float* out = (float*)d_out;

    int dim = in_sizes[2];
    int m = in_sizes[1] / dim;
    int n = in_sizes[0] / dim;

    const size_t MD = (size_t)m * dim;   // 1M elements
    const size_t MM = (size_t)m * m;

    // ws is ~256 MB (harness poison-fill shows 268 MB writes): disjoint layout, ~56 MB.
    char* cur = (char*)d_ws;
    auto alloc_f = [&](size_t nelem) { float* p = (float*)cur; cur += nelem * 4; return p; };
    auto alloc_s = [&](size_t nelem) { short* p = (short*)cur; cur += nelem * 2; return p; };
    float* V   = alloc_f(MD);
    float* G   = alloc_f(MM);
    short* Vh  = alloc_s(MD);
    short* Vl  = alloc_s(MD);
    short* Vth = alloc_s(MD);
    short* Vtl = alloc_s(MD);
    short* Gh  = alloc_s(MM);
    short* Gl  = alloc_s(MM);
    short* Th  = alloc_s(MM);
    short* Tl  = alloc_s(MM);
    short* Tth = alloc_s(MM);
    short* Ttl = alloc_s(MM);
    short* Wh  = alloc_s(MD);
    short* Wl  = alloc_s(MD);
    short* Qt  = alloc_s((size_t)dim * dim);
    short* tmph = alloc_s(MM / 2);      // max level: s=m/2, one pair: s*s = MM/4; margin
    short* tmpl = alloc_s(MM / 2);
    short* xh  = alloc_s((size_t)n * dim);

    k_normalize<<<m, 256, 0, stream>>>(vec, V, dim);
    k_split<<<1024, 256, 0, stream>>>(V, Vh, Vl, (int)(MD / 4));
    k_tsplit<<<dim3(dim / 32, m / 32), 256, 0, stream>>>(V, Vth, Vtl, m, dim);

    // G = V * V^T, upper-triangle blocks only; fp32 + split outputs
    k_nt64<3, 2><<<dim3(m / 64, m / 64), 256, 0, stream>>>(Vh, Vl, Vh, Vl, G, Gh, Gl,
                                                           dim, dim, dim, m);
    // diag-block inversion -> split T (row-major + transposed)
    k_baseinv2<<<(m / 64) * 16, 256, 0, stream>>>(G, Th, Tl, Tth, Ttl, m);
    // tree levels, all MFMA on split operands
    for (int s = 64; s < m; s <<= 1) {
        dim3 g(s / 64, s / 64, m / (2 * s));
        k_trimm<1><<<g, 256, 0, stream>>>(Gh, Gl, Tth, Ttl, tmph, tmpl, nullptr, nullptr, m, s);
        k_trimm<2><<<g, 256, 0, stream>>>(Th, Tl, tmph, tmpl, Th, Tl, Tth, Ttl, m, s);
    }

    // W[d][k] = sum_{j<=k} Vt[d][j] * Tt[k][j]  (triangular K-bound)
    k_nt64<1, 1><<<dim3(m / 64, dim / 64), 256, 0, stream>>>(Vth, Vtl, Tth, Ttl, nullptr, Wh, Wl,
                                                             m, m, m, m);
    // Qt[e][d] = delta - sum_k Vt[e][k] * W[d][k]
    k_nt64<2, 0><<<dim3(dim / 64, dim / 64), 256, 0, stream>>>(Vth, Vtl, Wh, Wl, nullptr, Qt, nullptr,
                                                               m, m, m, dim);

    // xh = bf16(x); out = xh * Qt^T + bias
    k_cast<<<2048, 256, 0, stream>>>(x, xh, (int)((size_t)n * dim / 4));
    k_apply3<<<dim3(dim / 128, n / 128), 256, 0, stream>>>(xh, Qt, bias, out, dim);
}